// Round 14
// baseline (88.929 us; speedup 1.0000x reference)
//
#include <hip/hip_runtime.h>

#define HALFB 0.5f
#define CAPB  0.1f
#define NSTAGE 8            // stages per block; stage = 32 rows = 16 KB

__device__ __forceinline__ float clip05(float z) {
    return fminf(fmaxf(z, -HALFB), HALFB);   // v_med3_f32
}

// 8-lane xor-reduce via DPP (pure VALU, no LDS pipe). Proven r10.
// 0xB1 = quad_perm xor1, 0x4E = quad_perm xor2, 0x141 = row_half_mirror.
template <int CTRL>
__device__ __forceinline__ float dppf(float v) {
    return __int_as_float(__builtin_amdgcn_update_dpp(
        __float_as_int(v), __float_as_int(v), CTRL, 0xF, 0xF, false));
}
__device__ __forceinline__ float red8f(float v) {
    v += dppf<0xB1>(v); v += dppf<0x4E>(v); v += dppf<0x141>(v); return v;
}
__device__ __forceinline__ float min8f(float v) {
    v = fminf(v, dppf<0xB1>(v)); v = fminf(v, dppf<0x4E>(v));
    v = fminf(v, dppf<0x141>(v)); return v;
}
__device__ __forceinline__ float max8f(float v) {
    v = fmaxf(v, dppf<0xB1>(v)); v = fmaxf(v, dppf<0x4E>(v));
    v = fmaxf(v, dppf<0x141>(v)); return v;
}

// Producer-consumer block: 6 waves = 4 solver + 2 mem.
// Mem waves stream input into a 2-slot LDS ring with linear float4 addressing;
// stage s+1's loads are ISSUED before the barrier that opens stage s's solve,
// so ~16KB/block of HBM reads are in flight under every solve window
// (stage time = max(mem, solve), not sum). Solver waves run the verbatim
// r10 Newton solver from LDS and store results directly to global.
// Raw s_barrier (no implicit vmcnt(0) drain) + "memory" clobbers for ordering.
__global__ __launch_bounds__(384, 6) void proj_kernel(
    const float* __restrict__ x, float* __restrict__ out, int nrows)
{
    __shared__ float4 tile[2][1024];         // 2 slots x 16 KB

    const int tid  = threadIdx.x;
    const int lane = tid & 63;
    const int w    = tid >> 6;               // 0..3 solver, 4..5 mem
    const size_t brow = (size_t)blockIdx.x * (32 * NSTAGE);  // block's first row

    if (w >= 4) {
        // ---------------- producer (mem) waves ----------------
        const int m = w - 4;                 // half of stage: 0 or 1
        const float4* __restrict__ gsrc = (const float4*)x + (brow << 5);
        const int lofs = (m << 9) + lane;    // m*512 + lane

        float4 buf[8];
        #pragma unroll
        for (int i = 0; i < 8; ++i)          // prologue: stage 0 loads
            buf[i] = gsrc[lofs + (i << 6)];

        for (int s = 0; s < NSTAGE; ++s) {
            float4* __restrict__ dst = &tile[s & 1][0];
            #pragma unroll
            for (int i = 0; i < 8; ++i)      // compiler inserts counted vmcnt
                dst[lofs + (i << 6)] = buf[i];
            asm volatile("s_waitcnt lgkmcnt(0)" ::: "memory");  // LDS visible
            if (s + 1 < NSTAGE) {            // issue next stage's loads NOW:
                const float4* __restrict__ gn = gsrc + ((size_t)(s + 1) << 10);
                #pragma unroll
                for (int i = 0; i < 8; ++i)
                    buf[i] = gn[lofs + (i << 6)];
            }
            __builtin_amdgcn_s_barrier();    // A: data for stage s ready
            asm volatile("" ::: "memory");
            __builtin_amdgcn_s_barrier();    // B: solvers done with slot
            asm volatile("" ::: "memory");
        }
    } else {
        // ---------------- consumer (solver) waves ----------------
        const int q    = lane & 7;           // eighth of row
        const int rloc = lane >> 3;          // row within wave's 8-row group
        const int srow = (w << 3) + rloc;    // row within the 32-row stage

        for (int s = 0; s < NSTAGE; ++s) {
            __builtin_amdgcn_s_barrier();    // A: wait for stage s data
            asm volatile("" ::: "memory");

            const float4* __restrict__ src = &tile[s & 1][0];
            float4 v[4];
            #pragma unroll
            for (int j = 0; j < 4; ++j)      // solver layout read (r13-proven)
                v[j] = src[(srow << 5) + (j << 3) + q];

            // ---- solver: verbatim round 10 (proven, absmax 1.95e-3) ----
            float s0a = 0.f, s0b = 0.f, s0c = 0.f, s0d = 0.f;
            float naa = 0.f, nab = 0.f, nac = 0.f, nad = 0.f;
            float mna = 3.0e38f, mnb = 3.0e38f, mxa = -3.0e38f, mxb = -3.0e38f;
            #pragma unroll
            for (int j = 0; j < 4; ++j) {
                s0a += clip05(v[j].x); s0b += clip05(v[j].y);
                s0c += clip05(v[j].z); s0d += clip05(v[j].w);
                naa += (fabsf(v[j].x) < HALFB) ? 1.f : 0.f;
                nab += (fabsf(v[j].y) < HALFB) ? 1.f : 0.f;
                nac += (fabsf(v[j].z) < HALFB) ? 1.f : 0.f;
                nad += (fabsf(v[j].w) < HALFB) ? 1.f : 0.f;
                mna = fminf(mna, fminf(v[j].x, v[j].y));
                mnb = fminf(mnb, fminf(v[j].z, v[j].w));
                mxa = fmaxf(mxa, fmaxf(v[j].x, v[j].y));
                mxb = fmaxf(mxb, fmaxf(v[j].z, v[j].w));
            }
            float g  = red8f((s0a + s0b) + (s0c + s0d));
            float na = red8f((naa + nab) + (nac + nad));
            const float vmn = min8f(fminf(mna, mnb));
            const float vmx = max8f(fmaxf(mxa, mxb));

            const float t = fminf(fmaxf(g, -CAPB), CAPB);
            float lo  = vmn - (HALFB + CAPB);
            float hi  = vmx + (HALFB + CAPB);
            float lam = 0.f;

            for (int it = 0; it < 20; ++it) {
                if (fabsf(g - t) <= 1e-4f) break;   // final division heals residual
                if (g > t) lo = lam; else hi = lam; // g decreasing in lam
                float ln;
                if (na > 0.f) {
                    ln = lam + (g - t) * __builtin_amdgcn_rcpf(na);
                    if (!(ln > lo && ln < hi)) ln = 0.5f * (lo + hi);
                } else {
                    ln = 0.5f * (lo + hi);
                }
                if (ln == lam) break;
                lam = ln;

                float ga = 0.f, gb = 0.f, gc = 0.f, gd = 0.f;
                float pa = 0.f, pb = 0.f, pc = 0.f, pd = 0.f;
                #pragma unroll
                for (int j = 0; j < 4; ++j) {
                    const float z0 = v[j].x - lam, z1 = v[j].y - lam;
                    const float z2 = v[j].z - lam, z3 = v[j].w - lam;
                    ga += clip05(z0); gb += clip05(z1);
                    gc += clip05(z2); gd += clip05(z3);
                    pa += (fabsf(z0) < HALFB) ? 1.f : 0.f;
                    pb += (fabsf(z1) < HALFB) ? 1.f : 0.f;
                    pc += (fabsf(z2) < HALFB) ? 1.f : 0.f;
                    pd += (fabsf(z3) < HALFB) ? 1.f : 0.f;
                }
                g  = red8f((ga + gb) + (gc + gd));
                na = red8f((pa + pb) + (pc + pd));
            }

            const float lam_f = (na > 0.f) ? lam + (g - t) / na : lam;
            // ---- end solver ----

            // direct global store (r10 pattern; write path proven insensitive)
            const size_t grow = brow + (size_t)(s << 5) + srow;
            float4* __restrict__ po = (float4*)out + (grow << 5) + q;
            #pragma unroll
            for (int j = 0; j < 4; ++j)
                po[j << 3] = make_float4(
                    clip05(v[j].x - lam_f), clip05(v[j].y - lam_f),
                    clip05(v[j].z - lam_f), clip05(v[j].w - lam_f));

            __builtin_amdgcn_s_barrier();    // B: done with slot s&1
            asm volatile("" ::: "memory");
        }
    }
}

extern "C" void kernel_launch(void* const* d_in, const int* in_sizes, int n_in,
                              void* d_out, int out_size, void* d_ws, size_t ws_size,
                              hipStream_t stream) {
    const float* x = (const float*)d_in[0];
    float* out     = (float*)d_out;
    const int nrows = out_size / 128;                 // 262144
    // 1024 blocks x (32 rows/stage x 8 stages) = 262144 rows exactly;
    // 4 blocks/CU resident (LDS 32KB x 4 = 128KB), tail-free.
    const int grid  = nrows / (32 * NSTAGE);          // 1024
    hipLaunchKernelGGL(proj_kernel, dim3(grid), dim3(384), 0, stream, x, out, nrows);
}

// Round 15
// 50.283 us; speedup vs baseline: 1.7686x; 1.7686x over previous
//
#include <hip/hip_runtime.h>

#define HALFB 0.5f
#define CAPB  0.1f
#define NB 8            // stages per wave; stage = 8 rows = 4 KB

__device__ __forceinline__ float clip05(float z) {
    return fminf(fmaxf(z, -HALFB), HALFB);   // v_med3_f32
}

// 8-lane xor-reduce via DPP (pure VALU). Proven r10.
// 0xB1 = quad_perm xor1, 0x4E = quad_perm xor2, 0x141 = row_half_mirror.
template <int CTRL>
__device__ __forceinline__ float dppf(float v) {
    return __int_as_float(__builtin_amdgcn_update_dpp(
        __float_as_int(v), __float_as_int(v), CTRL, 0xF, 0xF, false));
}
__device__ __forceinline__ float red8f(float v) {
    v += dppf<0xB1>(v); v += dppf<0x4E>(v); v += dppf<0x141>(v); return v;
}
__device__ __forceinline__ float min8f(float v) {
    v = fminf(v, dppf<0xB1>(v)); v = fminf(v, dppf<0x4E>(v));
    v = fminf(v, dppf<0x141>(v)); return v;
}
__device__ __forceinline__ float max8f(float v) {
    v = fmaxf(v, dppf<0xB1>(v)); v = fmaxf(v, dppf<0x4E>(v));
    v = fmaxf(v, dppf<0x141>(v)); return v;
}

// Wave-private async double-buffer via global_load_lds (no VGPR staging, so
// r14's spill failure is structurally impossible; no barriers — each wave owns
// its 2 x 4KB LDS slots). Per stage: issue 4 DMA (1KB linear each) for stage
// s+1 into the idle slot, s_waitcnt vmcnt(4) (stage s complete, s+1 in
// flight), solve stage s from LDS (verbatim r10 solver), store to global.
// Stage s+1's HBM latency hides under stage s's ~2200-cycle solve.
__global__ __launch_bounds__(256, 4) void proj_kernel(
    const float* __restrict__ x, float* __restrict__ out, int nrows)
{
    __shared__ float4 tile[2048];            // 4 waves x 2 slots x 256 f4 = 32 KB

    const int tid  = threadIdx.x;
    const int lane = tid & 63;
    const int w    = tid >> 6;
    const int q    = lane & 7;               // eighth of row
    const int rloc = lane >> 3;              // row within 8-row stage

    // wave owns 8*NB = 64 consecutive rows; stage s = rows [8s, 8s+8)
    const size_t wrow0 = ((size_t)(blockIdx.x * 4 + w)) * (8 * NB);
    const float4* __restrict__ gsrc = (const float4*)x + (wrow0 << 5);
    float4*       __restrict__ gdst = (float4*)out     + (wrow0 << 5);
    const int wbase = w << 9;                // wave's 512-f4 LDS region

    // prologue: DMA stage 0 -> slot 0 (4 x 1KB; wave-uniform LDS base,
    // HW writes base + lane*16; per-lane global address)
    #pragma unroll
    for (int i = 0; i < 4; ++i)
        __builtin_amdgcn_global_load_lds(
            (const __attribute__((address_space(1))) void*)(gsrc + (i << 6) + lane),
            (__attribute__((address_space(3))) void*)(&tile[wbase + (i << 6)]),
            16, 0, 0);

    for (int s = 0; s < NB; ++s) {
        const int slot = s & 1;

        if (s + 1 < NB) {                    // issue next stage into idle slot
            const float4* g = gsrc + ((size_t)(s + 1) << 8);
            float4* l = &tile[wbase + ((slot ^ 1) << 8)];
            #pragma unroll
            for (int i = 0; i < 4; ++i)
                __builtin_amdgcn_global_load_lds(
                    (const __attribute__((address_space(1))) void*)(g + (i << 6) + lane),
                    (__attribute__((address_space(3))) void*)(l + (i << 6)),
                    16, 0, 0);
            // wait stage s's DMA (in-order retirement: leaves only the 4 newest)
            asm volatile("s_waitcnt vmcnt(4)" ::: "memory");
        } else {
            asm volatile("s_waitcnt vmcnt(0)" ::: "memory");
        }
        __builtin_amdgcn_sched_barrier(0);   // rule 18: pin ds_reads after wait

        // solver-layout LDS read: lane (rloc,q) gets f4 {q, q+8, q+16, q+24} of row rloc
        const float4* src = &tile[wbase + (slot << 8)];
        float4 v[4];
        #pragma unroll
        for (int j = 0; j < 4; ++j)
            v[j] = src[(rloc << 5) + (j << 3) + q];

        // ---- solver: verbatim round 10 (proven 45.4us, absmax 1.95e-3) ----
        float s0a = 0.f, s0b = 0.f, s0c = 0.f, s0d = 0.f;
        float naa = 0.f, nab = 0.f, nac = 0.f, nad = 0.f;
        float mna = 3.0e38f, mnb = 3.0e38f, mxa = -3.0e38f, mxb = -3.0e38f;
        #pragma unroll
        for (int j = 0; j < 4; ++j) {
            s0a += clip05(v[j].x); s0b += clip05(v[j].y);
            s0c += clip05(v[j].z); s0d += clip05(v[j].w);
            naa += (fabsf(v[j].x) < HALFB) ? 1.f : 0.f;
            nab += (fabsf(v[j].y) < HALFB) ? 1.f : 0.f;
            nac += (fabsf(v[j].z) < HALFB) ? 1.f : 0.f;
            nad += (fabsf(v[j].w) < HALFB) ? 1.f : 0.f;
            mna = fminf(mna, fminf(v[j].x, v[j].y));
            mnb = fminf(mnb, fminf(v[j].z, v[j].w));
            mxa = fmaxf(mxa, fmaxf(v[j].x, v[j].y));
            mxb = fmaxf(mxb, fmaxf(v[j].z, v[j].w));
        }
        float g  = red8f((s0a + s0b) + (s0c + s0d));
        float na = red8f((naa + nab) + (nac + nad));
        const float vmn = min8f(fminf(mna, mnb));
        const float vmx = max8f(fmaxf(mxa, mxb));

        const float t = fminf(fmaxf(g, -CAPB), CAPB);
        float lo  = vmn - (HALFB + CAPB);
        float hi  = vmx + (HALFB + CAPB);
        float lam = 0.f;

        for (int it = 0; it < 20; ++it) {
            if (fabsf(g - t) <= 1e-4f) break;     // final division heals residual
            if (g > t) lo = lam; else hi = lam;   // g decreasing in lam
            float ln;
            if (na > 0.f) {
                ln = lam + (g - t) * __builtin_amdgcn_rcpf(na);
                if (!(ln > lo && ln < hi)) ln = 0.5f * (lo + hi);
            } else {
                ln = 0.5f * (lo + hi);
            }
            if (ln == lam) break;
            lam = ln;

            float ga = 0.f, gb = 0.f, gc = 0.f, gd = 0.f;
            float pa = 0.f, pb = 0.f, pc = 0.f, pd = 0.f;
            #pragma unroll
            for (int j = 0; j < 4; ++j) {
                const float z0 = v[j].x - lam, z1 = v[j].y - lam;
                const float z2 = v[j].z - lam, z3 = v[j].w - lam;
                ga += clip05(z0); gb += clip05(z1);
                gc += clip05(z2); gd += clip05(z3);
                pa += (fabsf(z0) < HALFB) ? 1.f : 0.f;
                pb += (fabsf(z1) < HALFB) ? 1.f : 0.f;
                pc += (fabsf(z2) < HALFB) ? 1.f : 0.f;
                pd += (fabsf(z3) < HALFB) ? 1.f : 0.f;
            }
            g  = red8f((ga + gb) + (gc + gd));
            na = red8f((pa + pb) + (pc + pd));
        }

        const float lam_f = (na > 0.f) ? lam + (g - t) / na : lam;
        // ---- end solver ----

        // direct global store, r10's proven pattern (8 x 128B segments/instr)
        float4* po = gdst + ((size_t)s << 8);
        #pragma unroll
        for (int j = 0; j < 4; ++j)
            po[(rloc << 5) + (j << 3) + q] = make_float4(
                clip05(v[j].x - lam_f), clip05(v[j].y - lam_f),
                clip05(v[j].z - lam_f), clip05(v[j].w - lam_f));
    }
}

extern "C" void kernel_launch(void* const* d_in, const int* in_sizes, int n_in,
                              void* d_out, int out_size, void* d_ws, size_t ws_size,
                              hipStream_t stream) {
    const float* x = (const float*)d_in[0];
    float* out     = (float*)d_out;
    const int nrows = out_size / 128;                 // 262144
    // 1024 blocks x (4 waves x 8 rows x 8 stages) = 262144 rows exactly;
    // 32 KB LDS/block -> 4 blocks/CU resident, tail-free.
    const int grid  = nrows / (4 * 8 * NB);           // 1024
    hipLaunchKernelGGL(proj_kernel, dim3(grid), dim3(256), 0, stream, x, out, nrows);
}

// Round 16
// 45.432 us; speedup vs baseline: 1.9574x; 1.1068x over previous
//
#include <hip/hip_runtime.h>

#define HALFB 0.5f
#define CAPB  0.1f

__device__ __forceinline__ float clip05(float z) {
    return fminf(fmaxf(z, -HALFB), HALFB);   // v_med3_f32
}

// 8-lane xor-reduce via DPP (pure VALU, no LDS pipe).
// 0xB1 = quad_perm xor1, 0x4E = quad_perm xor2, 0x141 = row_half_mirror
// (valid final stage: after xor1+xor2 each quad is uniform).
template <int CTRL>
__device__ __forceinline__ float dppf(float v) {
    return __int_as_float(__builtin_amdgcn_update_dpp(
        __float_as_int(v), __float_as_int(v), CTRL, 0xF, 0xF, false));
}
__device__ __forceinline__ float red8f(float v) {
    v += dppf<0xB1>(v); v += dppf<0x4E>(v); v += dppf<0x141>(v); return v;
}
__device__ __forceinline__ float min8f(float v) {
    v = fminf(v, dppf<0xB1>(v)); v = fminf(v, dppf<0x4E>(v));
    v = fminf(v, dppf<0x141>(v)); return v;
}
__device__ __forceinline__ float max8f(float v) {
    v = fmaxf(v, dppf<0xB1>(v)); v = fmaxf(v, dppf<0x4E>(v));
    v = fmaxf(v, dppf<0x141>(v)); return v;
}

// FINAL STRUCTURE (round 10, best of 15 rounds at 45.4us):
// 8 lanes per row, 16 elems (4 x float4) per lane; interleaved ownership
// (lane q owns float4s {q, q+8, q+16, q+24}) -> dense 64B lines per memory
// instruction (the round-8 +30% win). 8 rows/wave, 32768 waves, max TLP.
// Solver: safeguarded Newton on g(lam)=t with per-iteration n_act slope,
// residual early-exit, exact final division == reference's closed form over
// the active set (absmax 1.95e-3 = comparison floor, stable rounds 2-15).
//
// Why no pipelining/staging: this kernel sits at ~94% of the measured copy
// ceiling in CU-port bytes (268 MB irreducible / 45.4us = 5.9 TB/s vs 6.29
// copy bench). Five overlap mechanisms (in-wave MLP x3, LDS-linear staging,
// producer-consumer waves, async global_load_lds dbuf) all returned null or
// regressed (r5/r9/r12/r13/r14/r15) - the floor is the memory port, and the
// remaining ~7% over 42.6us is the unoverlapped tail of ~34% VALUBusy.
__global__ __launch_bounds__(256, 4) void proj_kernel(
    const float* __restrict__ x, float* __restrict__ out, int nrows)
{
    const int lane = threadIdx.x & 63;
    const int wid  = (blockIdx.x << 2) | (threadIdx.x >> 6);
    const int q    = lane & 7;                     // eighth of row
    int row = (wid << 3) | (lane >> 3);            // 8 rows per wave
    if (row >= nrows) row = nrows - 1;             // grid divides exactly

    const float4* __restrict__ px = (const float4*)x  + ((size_t)row << 5) + q;
    float4*       __restrict__ po = (float4*)out      + ((size_t)row << 5) + q;

    float4 v[4];
    #pragma unroll
    for (int j = 0; j < 4; ++j) v[j] = px[j << 3];   // stride 8 float4 = 128B

    // init sweep: 4-way partial trees for s0 / n_act / min / max
    float s0a = 0.f, s0b = 0.f, s0c = 0.f, s0d = 0.f;
    float naa = 0.f, nab = 0.f, nac = 0.f, nad = 0.f;
    float mna = 3.0e38f, mnb = 3.0e38f, mxa = -3.0e38f, mxb = -3.0e38f;
    #pragma unroll
    for (int j = 0; j < 4; ++j) {
        s0a += clip05(v[j].x); s0b += clip05(v[j].y);
        s0c += clip05(v[j].z); s0d += clip05(v[j].w);
        naa += (fabsf(v[j].x) < HALFB) ? 1.f : 0.f;
        nab += (fabsf(v[j].y) < HALFB) ? 1.f : 0.f;
        nac += (fabsf(v[j].z) < HALFB) ? 1.f : 0.f;
        nad += (fabsf(v[j].w) < HALFB) ? 1.f : 0.f;
        mna = fminf(mna, fminf(v[j].x, v[j].y));
        mnb = fminf(mnb, fminf(v[j].z, v[j].w));
        mxa = fmaxf(mxa, fmaxf(v[j].x, v[j].y));
        mxb = fmaxf(mxb, fmaxf(v[j].z, v[j].w));
    }
    float g  = red8f((s0a + s0b) + (s0c + s0d));
    float na = red8f((naa + nab) + (nac + nad));
    const float vmn = min8f(fminf(mna, mnb));
    const float vmx = max8f(fmaxf(mxa, mxb));

    const float t = fminf(fmaxf(g, -CAPB), CAPB);
    float lo  = vmn - (HALFB + CAPB);
    float hi  = vmx + (HALFB + CAPB);
    float lam = 0.f;

    for (int it = 0; it < 20; ++it) {
        if (fabsf(g - t) <= 1e-4f) break;     // final division heals residual
        if (g > t) lo = lam; else hi = lam;   // g decreasing in lam
        float ln;
        if (na > 0.f) {
            ln = lam + (g - t) * __builtin_amdgcn_rcpf(na);
            if (!(ln > lo && ln < hi)) ln = 0.5f * (lo + hi);
        } else {
            ln = 0.5f * (lo + hi);
        }
        if (ln == lam) break;
        lam = ln;

        float ga = 0.f, gb = 0.f, gc = 0.f, gd = 0.f;
        float pa = 0.f, pb = 0.f, pc = 0.f, pd = 0.f;
        #pragma unroll
        for (int j = 0; j < 4; ++j) {
            const float z0 = v[j].x - lam, z1 = v[j].y - lam;
            const float z2 = v[j].z - lam, z3 = v[j].w - lam;
            ga += clip05(z0); gb += clip05(z1);
            gc += clip05(z2); gd += clip05(z3);
            pa += (fabsf(z0) < HALFB) ? 1.f : 0.f;
            pb += (fabsf(z1) < HALFB) ? 1.f : 0.f;
            pc += (fabsf(z2) < HALFB) ? 1.f : 0.f;
            pd += (fabsf(z3) < HALFB) ? 1.f : 0.f;
        }
        g  = red8f((ga + gb) + (gc + gd));
        na = red8f((pa + pb) + (pc + pd));
    }

    // exact closed form over the active set (== reference's last step)
    const float lam_f = (na > 0.f) ? lam + (g - t) / na : lam;

    #pragma unroll
    for (int j = 0; j < 4; ++j) {
        po[j << 3] = make_float4(clip05(v[j].x - lam_f), clip05(v[j].y - lam_f),
                                 clip05(v[j].z - lam_f), clip05(v[j].w - lam_f));
    }
}

extern "C" void kernel_launch(void* const* d_in, const int* in_sizes, int n_in,
                              void* d_out, int out_size, void* d_ws, size_t ws_size,
                              hipStream_t stream) {
    const float* x = (const float*)d_in[0];
    float* out     = (float*)d_out;
    const int nrows = out_size / 128;             // 262144
    const int grid  = (nrows + 31) / 32;          // 8192 blocks, 32 rows each
    hipLaunchKernelGGL(proj_kernel, dim3(grid), dim3(256), 0, stream, x, out, nrows);
}